// Round 1
// baseline (735.433 us; speedup 1.0000x reference)
//
#include <hip/hip_runtime.h>

// Channel attention block (Restormer MDTA style), B=4 C=64 H=W=256 HEADS=8.
// Plan: pw-conv GEMMs (f32 VALU, bf16 intermediates), fused dw+norms+dots
// (q,k never stored), attn+proj folded into per-batch 64x64 matrix M.

#define HWN 65536
#define BN 4
typedef unsigned short u16;

__device__ __forceinline__ float bf2f(u16 u) {
    return __uint_as_float(((unsigned int)u) << 16);
}
__device__ __forceinline__ u16 f2bf(float f) {  // RNE bf16 round
    unsigned int x = __float_as_uint(f);
    x += 0x7FFFu + ((x >> 16) & 1u);
    return (u16)(x >> 16);
}

// ---------------------------------------------------------------------------
// Pointwise (1x1 conv) GEMM: out[b][oc][p] = sum_ic w[ic][oc] * in[b][ic][p]
// block 256 = G ocgroups x T threads; each thread: 16 oc x 4 px register tile.
// W_OIC: global weights are [oc][ic] (conv layout) -> transpose while staging.
// ---------------------------------------------------------------------------
template<int OC, bool IN_BF16, bool OUT_BF16, bool W_OIC, bool W_PERB>
__global__ __launch_bounds__(256) void pw_gemm(const void* __restrict__ in_v,
                                               const float* __restrict__ w_g,
                                               void* __restrict__ out_v)
{
    constexpr int G = OC / 16;
    constexpr int T = 256 / G;
    constexpr int PXB = T * 4;
    constexpr int NCHUNK = HWN / PXB;
    __shared__ float wlds[64 * OC];

    const int tid = threadIdx.x;
    const int b = blockIdx.y;
    const float* wsrc = w_g + (W_PERB ? b * 64 * OC : 0);

    for (int idx = tid * 4; idx < 64 * OC; idx += 1024) {
        float4 wv = *reinterpret_cast<const float4*>(wsrc + idx);
        if (W_OIC) {  // global [oc][64] -> lds [ic][OC]
            int oc = idx >> 6, ic0 = idx & 63;
            wlds[(ic0 + 0) * OC + oc] = wv.x;
            wlds[(ic0 + 1) * OC + oc] = wv.y;
            wlds[(ic0 + 2) * OC + oc] = wv.z;
            wlds[(ic0 + 3) * OC + oc] = wv.w;
        } else {      // already [ic][OC]
            *reinterpret_cast<float4*>(&wlds[idx]) = wv;
        }
    }
    __syncthreads();

    const int og = tid / T, tl = tid % T;
    const int ocb = og * 16;
    const size_t inb = (size_t)b * 64 * HWN;

    for (int chunk = blockIdx.x; chunk < NCHUNK; chunk += gridDim.x) {
        const int p0 = chunk * PXB + tl * 4;
        float acc[16][4];
#pragma unroll
        for (int o = 0; o < 16; ++o) {
            acc[o][0] = 0.f; acc[o][1] = 0.f; acc[o][2] = 0.f; acc[o][3] = 0.f;
        }
#pragma unroll 4
        for (int ic = 0; ic < 64; ++ic) {
            float x0, x1, x2, x3;
            if (IN_BF16) {
                ushort4 u = *reinterpret_cast<const ushort4*>(
                    (const u16*)in_v + inb + (size_t)ic * HWN + p0);
                x0 = bf2f(u.x); x1 = bf2f(u.y); x2 = bf2f(u.z); x3 = bf2f(u.w);
            } else {
                float4 f = *reinterpret_cast<const float4*>(
                    (const float*)in_v + inb + (size_t)ic * HWN + p0);
                x0 = f.x; x1 = f.y; x2 = f.z; x3 = f.w;
            }
            const float* wr = &wlds[ic * OC + ocb];  // uniform -> LDS broadcast
#pragma unroll
            for (int o = 0; o < 16; ++o) {
                const float wv = wr[o];
                acc[o][0] = fmaf(wv, x0, acc[o][0]);
                acc[o][1] = fmaf(wv, x1, acc[o][1]);
                acc[o][2] = fmaf(wv, x2, acc[o][2]);
                acc[o][3] = fmaf(wv, x3, acc[o][3]);
            }
        }
#pragma unroll
        for (int o = 0; o < 16; ++o) {
            const size_t ob = ((size_t)b * OC + ocb + o) * HWN + p0;
            if (OUT_BF16) {
                ushort4 u;
                u.x = f2bf(acc[o][0]); u.y = f2bf(acc[o][1]);
                u.z = f2bf(acc[o][2]); u.w = f2bf(acc[o][3]);
                *reinterpret_cast<ushort4*>((u16*)out_v + ob) = u;
            } else {
                float4 f;
                f.x = acc[o][0]; f.y = acc[o][1]; f.z = acc[o][2]; f.w = acc[o][3];
                *reinterpret_cast<float4*>((float*)out_v + ob) = f;
            }
        }
    }
}

// ---------------------------------------------------------------------------
// Fused: dw3x3 on q-channels and k-channels of one head (zero pad),
// accumulate sumsq(q), sumsq(k), and qk[c][d] dot products. No q/k stores.
// grid (32 rowchunks, 8 heads, 4 b); 256 threads = one w column each, 8 rows.
// ---------------------------------------------------------------------------
__global__ __launch_bounds__(256) void qk_dots(const u16* __restrict__ tq,
                                               const u16* __restrict__ tkv,
                                               const float* __restrict__ qdw,
                                               const float* __restrict__ kvdw,
                                               float* __restrict__ ssq_q,
                                               float* __restrict__ ssq_k,
                                               float* __restrict__ qkout)
{
    const int b = blockIdx.z, hd = blockIdx.y;
    const int r0 = blockIdx.x * 8;
    const int w = threadIdx.x;

    __shared__ float wq[72], wk[72];
    if (threadIdx.x < 72)       wq[threadIdx.x] = qdw[hd * 72 + threadIdx.x];
    else if (threadIdx.x < 144) wk[threadIdx.x - 72] = kvdw[hd * 72 + (threadIdx.x - 72)];
    __syncthreads();

    float acc[8][8] = {{0.f}};
    float sq[8] = {0.f}, sk[8] = {0.f};
    const u16* qb = tq  + (size_t)(b * 64  + hd * 8) * HWN;
    const u16* kb = tkv + (size_t)(b * 128 + hd * 8) * HWN;

    for (int r = 0; r < 8; ++r) {
        const int h = r0 + r;
        const int base = h * 256 + w;
        const float mt = (h > 0) ? 1.f : 0.f, mb = (h < 255) ? 1.f : 0.f;
        const float ml = (w > 0) ? 1.f : 0.f, mr = (w < 255) ? 1.f : 0.f;
        const int ot = (h > 0) ? -256 : 0, ob2 = (h < 255) ? 256 : 0;
        const int ol = (w > 0) ? -1 : 0,  orr = (w < 255) ? 1 : 0;
        const int off[9] = {base+ot+ol, base+ot, base+ot+orr,
                            base+ol,    base,    base+orr,
                            base+ob2+ol,base+ob2,base+ob2+orr};
        const float m[9] = {mt*ml, mt, mt*mr, ml, 1.f, mr, mb*ml, mb, mb*mr};

        float qv[8], kv[8];
#pragma unroll
        for (int c = 0; c < 8; ++c) {
            const u16* p = qb + (size_t)c * HWN;
            float s = 0.f;
#pragma unroll
            for (int j = 0; j < 9; ++j) s = fmaf(wq[c*9+j], m[j] * bf2f(p[off[j]]), s);
            qv[c] = s; sq[c] = fmaf(s, s, sq[c]);
        }
#pragma unroll
        for (int c = 0; c < 8; ++c) {
            const u16* p = kb + (size_t)c * HWN;
            float s = 0.f;
#pragma unroll
            for (int j = 0; j < 9; ++j) s = fmaf(wk[c*9+j], m[j] * bf2f(p[off[j]]), s);
            kv[c] = s; sk[c] = fmaf(s, s, sk[c]);
        }
#pragma unroll
        for (int c = 0; c < 8; ++c)
#pragma unroll
            for (int d = 0; d < 8; ++d)
                acc[c][d] = fmaf(qv[c], kv[d], acc[c][d]);
    }

    // block reduce 64 dots + 8 + 8 sumsq, one atomic each per block
    const int lane = threadIdx.x & 63, wid = threadIdx.x >> 6;
    __shared__ float red[4][80];
#pragma unroll
    for (int i = 0; i < 80; ++i) {
        float x = (i < 64) ? acc[i >> 3][i & 7] : (i < 72) ? sq[i - 64] : sk[i - 72];
#pragma unroll
        for (int o = 32; o > 0; o >>= 1) x += __shfl_down(x, o, 64);
        if (lane == 0) red[wid][i] = x;
    }
    __syncthreads();
    if (threadIdx.x < 80) {
        const int t = threadIdx.x;
        float s = red[0][t] + red[1][t] + red[2][t] + red[3][t];
        float* dst;
        if (t < 64)      dst = qkout + (size_t)((b*8 + hd)*8 + (t >> 3)) * 8 + (t & 7);
        else if (t < 72) dst = ssq_q + b * 64 + hd * 8 + (t - 64);
        else             dst = ssq_k + b * 64 + hd * 8 + (t - 72);
        atomicAdd(dst, s);
    }
}

// ---------------------------------------------------------------------------
// Depthwise 3x3 for v channels (kv channels 64..127), zero pad, bf16 out.
// One thread = 4 consecutive w pixels.
// ---------------------------------------------------------------------------
__global__ __launch_bounds__(256) void dw_v(const u16* __restrict__ tkv,
                                            const float* __restrict__ kvdw,
                                            u16* __restrict__ vout)
{
    const int qid = blockIdx.x * 256 + threadIdx.x;   // 0 .. 4194303
    const int w0 = (qid & 63) * 4;
    const int h  = (qid >> 6) & 255;
    const int ch = (qid >> 14) & 63;
    const int b  = qid >> 20;

    const u16* p = tkv + (size_t)(b * 128 + 64 + ch) * HWN;
    const float* wd = kvdw + (64 + ch) * 9;

    float a0 = 0.f, a1 = 0.f, a2 = 0.f, a3 = 0.f;
    const float mL = (w0 > 0) ? 1.f : 0.f;
    const float mR = (w0 < 252) ? 1.f : 0.f;
    const int iL = (w0 > 0) ? w0 - 1 : 0;
    const int iR = (w0 < 252) ? w0 + 4 : 255;
#pragma unroll
    for (int j = 0; j < 3; ++j) {
        const int hh = h - 1 + j;
        if (hh < 0 || hh > 255) continue;  // uniform across the wave
        const int rb = hh * 256;
        float xm1 = bf2f(p[rb + iL]) * mL;
        ushort4 mu = *reinterpret_cast<const ushort4*>(p + rb + w0);
        float x0 = bf2f(mu.x), x1 = bf2f(mu.y), x2 = bf2f(mu.z), x3 = bf2f(mu.w);
        float x4 = bf2f(p[rb + iR]) * mR;
        const float wa = wd[j*3+0], wb = wd[j*3+1], wc = wd[j*3+2];
        a0 = fmaf(wa, xm1, a0); a0 = fmaf(wb, x0, a0); a0 = fmaf(wc, x1, a0);
        a1 = fmaf(wa, x0,  a1); a1 = fmaf(wb, x1, a1); a1 = fmaf(wc, x2, a1);
        a2 = fmaf(wa, x1,  a2); a2 = fmaf(wb, x2, a2); a2 = fmaf(wc, x3, a2);
        a3 = fmaf(wa, x2,  a3); a3 = fmaf(wb, x3, a3); a3 = fmaf(wc, x4, a3);
    }
    ushort4 o;
    o.x = f2bf(a0); o.y = f2bf(a1); o.z = f2bf(a2); o.w = f2bf(a3);
    *reinterpret_cast<ushort4*>(vout + (size_t)(b * 64 + ch) * HWN + h * 256 + w0) = o;
}

// ---------------------------------------------------------------------------
// Tiny: norms -> attn softmax -> fold proj: M_t[b][cv][oc] (f32).
// grid 4 (b), 64 threads.
// ---------------------------------------------------------------------------
__global__ __launch_bounds__(64) void build_m(const float* __restrict__ ssq_q,
                                              const float* __restrict__ ssq_k,
                                              const float* __restrict__ qk,
                                              const float* __restrict__ temp,
                                              const float* __restrict__ projw,
                                              float* __restrict__ Mt)
{
    const int b = blockIdx.x, t = threadIdx.x;
    __shared__ float attn[8][8][8];  // [head][c][d]
    {
        const int hd = t >> 3, c = t & 7;
        const float nq = fmaxf(sqrtf(ssq_q[b * 64 + hd * 8 + c]), 1e-12f);
        float s[8];
        float mx = -1e30f;
#pragma unroll
        for (int d = 0; d < 8; ++d) {
            const float nk = fmaxf(sqrtf(ssq_k[b * 64 + hd * 8 + d]), 1e-12f);
            s[d] = qk[(size_t)((b*8 + hd)*8 + c) * 8 + d] / (nq * nk) * temp[hd];
            mx = fmaxf(mx, s[d]);
        }
        float sum = 0.f;
#pragma unroll
        for (int d = 0; d < 8; ++d) { s[d] = expf(s[d] - mx); sum += s[d]; }
        const float inv = 1.f / sum;
#pragma unroll
        for (int d = 0; d < 8; ++d) attn[hd][c][d] = s[d] * inv;
    }
    __syncthreads();
    // t = oc; M_t[cv][oc] = sum_cl P[oc][h(cv)*8+cl] * attn[h(cv)][cl][d(cv)]
    for (int hh = 0; hh < 8; ++hh) {
        float p8[8];
#pragma unroll
        for (int cl = 0; cl < 8; ++cl) p8[cl] = projw[t * 64 + hh * 8 + cl];
#pragma unroll
        for (int d = 0; d < 8; ++d) {
            float a = 0.f;
#pragma unroll
            for (int cl = 0; cl < 8; ++cl) a = fmaf(p8[cl], attn[hh][cl][d], a);
            Mt[b * 4096 + (hh * 8 + d) * 64 + t] = a;
        }
    }
}

// ---------------------------------------------------------------------------
extern "C" void kernel_launch(void* const* d_in, const int* in_sizes, int n_in,
                              void* d_out, int out_size, void* d_ws, size_t ws_size,
                              hipStream_t stream)
{
    const float* input1  = (const float*)d_in[0];
    const float* input2  = (const float*)d_in[1];
    const float* q_w     = (const float*)d_in[2];
    const float* q_dw_w  = (const float*)d_in[3];
    const float* kv_w    = (const float*)d_in[4];
    const float* kv_dw_w = (const float*)d_in[5];
    const float* proj_w  = (const float*)d_in[6];
    const float* temp    = (const float*)d_in[7];
    float* out = (float*)d_out;

    char* ws = (char*)d_ws;
    // layout: t_kv (67108864 B) | t_q (33554432 B, reused as v) | accumulators
    u16* t_kv = (u16*)ws;
    u16* t_q  = (u16*)(ws + 67108864);
    u16* v    = t_q;  // alias: t_q dead after qk_dots (stream-ordered)
    float* accs  = (float*)(ws + 100663296);
    float* ssq_q = accs;          // 256
    float* ssq_k = accs + 256;    // 256
    float* qk    = accs + 512;    // 2048
    float* Mt    = accs + 2560;   // 16384
    if (ws_size < 100663296ull + (2560ull + 16384ull) * 4ull) return;

    hipMemsetAsync(accs, 0, 2560 * sizeof(float), stream);

    // K1: t_q = 1x1(input1, q_w)   [bf16 out]
    pw_gemm<64, false, true, true, false><<<dim3(128, 4), 256, 0, stream>>>(input1, q_w, t_q);
    // K2: t_kv = 1x1(input2, kv_w) [bf16 out]
    pw_gemm<128, false, true, true, false><<<dim3(128, 4), 256, 0, stream>>>(input2, kv_w, t_kv);
    // K3: dw(q), dw(k), sumsq, qk dots (atomics)
    qk_dots<<<dim3(32, 8, 4), 256, 0, stream>>>(t_q, t_kv, q_dw_w, kv_dw_w, ssq_q, ssq_k, qk);
    // K4: v = dw(t_v)  (writes into t_q's space)
    dw_v<<<16384, 256, 0, stream>>>(t_kv, kv_dw_w, v);
    // K5: M_t[b] = proj @ blockdiag(softmax(qk/(nq nk) * temp))
    build_m<<<4, 64, 0, stream>>>(ssq_q, ssq_k, qk, temp, proj_w, Mt);
    // K6: out = M_b @ v   [f32 out]
    pw_gemm<64, true, false, false, true><<<dim3(128, 4), 256, 0, stream>>>(v, Mt, out);
}

// Round 2
// 494.524 us; speedup vs baseline: 1.4872x; 1.4872x over previous
//
#include <hip/hip_runtime.h>

// Channel attention block (Restormer MDTA style), B=4 C=64 H=W=256 HEADS=8.
// R1: qk_dots rewritten as row-wave stencil (ushort4 loads + shfl edges,
// reduce-scatter butterfly). pw_gemm grids widened.

#define HWN 65536
typedef unsigned short u16;

__device__ __forceinline__ float bf2f(u16 u) {
    return __uint_as_float(((unsigned int)u) << 16);
}
__device__ __forceinline__ u16 f2bf(float f) {  // RNE bf16 round
    unsigned int x = __float_as_uint(f);
    x += 0x7FFFu + ((x >> 16) & 1u);
    return (u16)(x >> 16);
}

// ---------------------------------------------------------------------------
// Pointwise (1x1 conv) GEMM: out[b][oc][p] = sum_ic w[ic][oc] * in[b][ic][p]
// block 256 = G ocgroups x T threads; each thread: 16 oc x 4 px register tile.
// ---------------------------------------------------------------------------
template<int OC, bool IN_BF16, bool OUT_BF16, bool W_OIC, bool W_PERB>
__global__ __launch_bounds__(256) void pw_gemm(const void* __restrict__ in_v,
                                               const float* __restrict__ w_g,
                                               void* __restrict__ out_v)
{
    constexpr int G = OC / 16;
    constexpr int T = 256 / G;
    constexpr int PXB = T * 4;
    constexpr int NCHUNK = HWN / PXB;
    __shared__ float wlds[64 * OC];

    const int tid = threadIdx.x;
    const int b = blockIdx.y;
    const float* wsrc = w_g + (W_PERB ? b * 64 * OC : 0);

    for (int idx = tid * 4; idx < 64 * OC; idx += 1024) {
        float4 wv = *reinterpret_cast<const float4*>(wsrc + idx);
        if (W_OIC) {  // global [oc][64] -> lds [ic][OC]
            int oc = idx >> 6, ic0 = idx & 63;
            wlds[(ic0 + 0) * OC + oc] = wv.x;
            wlds[(ic0 + 1) * OC + oc] = wv.y;
            wlds[(ic0 + 2) * OC + oc] = wv.z;
            wlds[(ic0 + 3) * OC + oc] = wv.w;
        } else {      // already [ic][OC]
            *reinterpret_cast<float4*>(&wlds[idx]) = wv;
        }
    }
    __syncthreads();

    const int og = tid / T, tl = tid % T;
    const int ocb = og * 16;
    const size_t inb = (size_t)b * 64 * HWN;

    for (int chunk = blockIdx.x; chunk < NCHUNK; chunk += gridDim.x) {
        const int p0 = chunk * PXB + tl * 4;
        float acc[16][4];
#pragma unroll
        for (int o = 0; o < 16; ++o) {
            acc[o][0] = 0.f; acc[o][1] = 0.f; acc[o][2] = 0.f; acc[o][3] = 0.f;
        }
#pragma unroll 4
        for (int ic = 0; ic < 64; ++ic) {
            float x0, x1, x2, x3;
            if (IN_BF16) {
                ushort4 u = *reinterpret_cast<const ushort4*>(
                    (const u16*)in_v + inb + (size_t)ic * HWN + p0);
                x0 = bf2f(u.x); x1 = bf2f(u.y); x2 = bf2f(u.z); x3 = bf2f(u.w);
            } else {
                float4 f = *reinterpret_cast<const float4*>(
                    (const float*)in_v + inb + (size_t)ic * HWN + p0);
                x0 = f.x; x1 = f.y; x2 = f.z; x3 = f.w;
            }
            const float* wr = &wlds[ic * OC + ocb];  // uniform -> LDS broadcast
#pragma unroll
            for (int o = 0; o < 16; ++o) {
                const float wv = wr[o];
                acc[o][0] = fmaf(wv, x0, acc[o][0]);
                acc[o][1] = fmaf(wv, x1, acc[o][1]);
                acc[o][2] = fmaf(wv, x2, acc[o][2]);
                acc[o][3] = fmaf(wv, x3, acc[o][3]);
            }
        }
#pragma unroll
        for (int o = 0; o < 16; ++o) {
            const size_t ob = ((size_t)b * OC + ocb + o) * HWN + p0;
            if (OUT_BF16) {
                ushort4 u;
                u.x = f2bf(acc[o][0]); u.y = f2bf(acc[o][1]);
                u.z = f2bf(acc[o][2]); u.w = f2bf(acc[o][3]);
                *reinterpret_cast<ushort4*>((u16*)out_v + ob) = u;
            } else {
                float4 f;
                f.x = acc[o][0]; f.y = acc[o][1]; f.z = acc[o][2]; f.w = acc[o][3];
                *reinterpret_cast<float4*>((float*)out_v + ob) = f;
            }
        }
    }
}

// ---------------------------------------------------------------------------
// qk_dots (R1 rewrite): one wave = one image row (64 lanes x 4 px = 256 px).
// Per (channel, tap row): one ushort4 load; w-neighbors via shfl of adjacent
// lanes (wave edge == image edge -> zero pad). dw(q), dw(k) on the fly,
// accumulate qk[c][d] dots + sumsq. Reduce-scatter butterfly -> 1 atomic/lane.
// grid (32 rowchunks, 8 heads, 4 b); 256 thr = 4 waves x RPW rows each.
// ---------------------------------------------------------------------------
#define RPW 2

__global__ __launch_bounds__(256) void qk_dots(const u16* __restrict__ tq,
                                               const u16* __restrict__ tkv,
                                               const float* __restrict__ qdw,
                                               const float* __restrict__ kvdw,
                                               float* __restrict__ ssq_q,
                                               float* __restrict__ ssq_k,
                                               float* __restrict__ qkout)
{
    const int b = blockIdx.z, hd = blockIdx.y;
    const int lane = threadIdx.x & 63, wid = threadIdx.x >> 6;
    const int row0 = blockIdx.x * (4 * RPW) + wid * RPW;

    __shared__ float wq[72], wk[72];
    if (threadIdx.x < 72)       wq[threadIdx.x] = qdw[hd * 72 + threadIdx.x];
    else if (threadIdx.x < 144) wk[threadIdx.x - 72] = kvdw[hd * 72 + (threadIdx.x - 72)];
    __syncthreads();

    const u16* qb = tq  + (size_t)(b * 64  + hd * 8) * HWN;
    const u16* kb = tkv + (size_t)(b * 128 + hd * 8) * HWN;
    const int wo = lane * 4;

    float A[64];
#pragma unroll
    for (int i = 0; i < 64; ++i) A[i] = 0.f;
    float sq[8] = {0.f, 0.f, 0.f, 0.f, 0.f, 0.f, 0.f, 0.f};
    float sk[8] = {0.f, 0.f, 0.f, 0.f, 0.f, 0.f, 0.f, 0.f};

    // 3x3 depthwise for a 4-px strip of row h, channel base cb+c, weights wtab
#define DW4(PBASE, C, WTAB, A0, A1, A2, A3)                                    \
    {                                                                          \
        A0 = 0.f; A1 = 0.f; A2 = 0.f; A3 = 0.f;                                \
        const u16* p_ = (PBASE) + (size_t)(C) * HWN;                           \
        _Pragma("unroll")                                                      \
        for (int j = 0; j < 3; ++j) {                                          \
            const int hh = h - 1 + j;                                          \
            if (hh >= 0 && hh <= 255) {                                        \
                ushort4 u_ = *reinterpret_cast<const ushort4*>(p_ + hh * 256 + wo); \
                float x0 = bf2f(u_.x), x1 = bf2f(u_.y);                        \
                float x2 = bf2f(u_.z), x3 = bf2f(u_.w);                        \
                float xm1 = __shfl_up(x3, 1);  if (lane == 0)  xm1 = 0.f;      \
                float x4  = __shfl_down(x0, 1); if (lane == 63) x4 = 0.f;      \
                const float wa = WTAB[(C) * 9 + j * 3 + 0];                    \
                const float wb = WTAB[(C) * 9 + j * 3 + 1];                    \
                const float wc = WTAB[(C) * 9 + j * 3 + 2];                    \
                A0 = fmaf(wa, xm1, A0); A0 = fmaf(wb, x0, A0); A0 = fmaf(wc, x1, A0); \
                A1 = fmaf(wa, x0,  A1); A1 = fmaf(wb, x1, A1); A1 = fmaf(wc, x2, A1); \
                A2 = fmaf(wa, x1,  A2); A2 = fmaf(wb, x2, A2); A2 = fmaf(wc, x3, A2); \
                A3 = fmaf(wa, x2,  A3); A3 = fmaf(wb, x3, A3); A3 = fmaf(wc, x4, A3); \
            }                                                                  \
        }                                                                      \
    }

    for (int r = 0; r < RPW; ++r) {
        const int h = row0 + r;
        float qv[8][4];
#pragma unroll
        for (int c = 0; c < 8; ++c) {
            float a0, a1, a2, a3;
            DW4(qb, c, wq, a0, a1, a2, a3);
            qv[c][0] = a0; qv[c][1] = a1; qv[c][2] = a2; qv[c][3] = a3;
            sq[c] = fmaf(a0, a0, sq[c]); sq[c] = fmaf(a1, a1, sq[c]);
            sq[c] = fmaf(a2, a2, sq[c]); sq[c] = fmaf(a3, a3, sq[c]);
        }
#pragma unroll
        for (int d = 0; d < 8; ++d) {
            float k0, k1, k2, k3;
            DW4(kb, d, wk, k0, k1, k2, k3);
            sk[d] = fmaf(k0, k0, sk[d]); sk[d] = fmaf(k1, k1, sk[d]);
            sk[d] = fmaf(k2, k2, sk[d]); sk[d] = fmaf(k3, k3, sk[d]);
#pragma unroll
            for (int c = 0; c < 8; ++c) {
                float a = A[c * 8 + d];
                a = fmaf(qv[c][0], k0, a); a = fmaf(qv[c][1], k1, a);
                a = fmaf(qv[c][2], k2, a); a = fmaf(qv[c][3], k3, a);
                A[c * 8 + d] = a;
            }
        }
    }

    // reduce-scatter butterfly: after all steps lane l holds total of A[l]
#define REDSTEP(B, arr)                                                        \
    {                                                                          \
        const bool hi_ = (lane & (B)) != 0;                                    \
        _Pragma("unroll")                                                      \
        for (int i = 0; i < (B); ++i) {                                        \
            float keep_ = hi_ ? arr[i + (B)] : arr[i];                         \
            float send_ = hi_ ? arr[i] : arr[i + (B)];                         \
            arr[i] = keep_ + __shfl_xor(send_, (B));                           \
        }                                                                      \
    }
    REDSTEP(32, A) REDSTEP(16, A) REDSTEP(8, A)
    REDSTEP(4, A)  REDSTEP(2, A)  REDSTEP(1, A)
    atomicAdd(qkout + (size_t)(b * 8 + hd) * 64 + lane, A[0]);

    float S[16];
#pragma unroll
    for (int c = 0; c < 8; ++c) { S[c] = sq[c]; S[8 + c] = sk[c]; }
    REDSTEP(8, S) REDSTEP(4, S) REDSTEP(2, S) REDSTEP(1, S)
    float s = S[0];
    s += __shfl_xor(s, 16);
    s += __shfl_xor(s, 32);
    if (lane < 16) {
        float* dst = (lane < 8) ? (ssq_q + b * 64 + hd * 8 + lane)
                                : (ssq_k + b * 64 + hd * 8 + lane - 8);
        atomicAdd(dst, s);
    }
#undef DW4
#undef REDSTEP
}

// ---------------------------------------------------------------------------
// Depthwise 3x3 for v channels (kv channels 64..127), zero pad, bf16 out.
// ---------------------------------------------------------------------------
__global__ __launch_bounds__(256) void dw_v(const u16* __restrict__ tkv,
                                            const float* __restrict__ kvdw,
                                            u16* __restrict__ vout)
{
    const int qid = blockIdx.x * 256 + threadIdx.x;   // 0 .. 4194303
    const int w0 = (qid & 63) * 4;
    const int h  = (qid >> 6) & 255;
    const int ch = (qid >> 14) & 63;
    const int b  = qid >> 20;

    const u16* p = tkv + (size_t)(b * 128 + 64 + ch) * HWN;
    const float* wd = kvdw + (64 + ch) * 9;

    float a0 = 0.f, a1 = 0.f, a2 = 0.f, a3 = 0.f;
    const float mL = (w0 > 0) ? 1.f : 0.f;
    const float mR = (w0 < 252) ? 1.f : 0.f;
    const int iL = (w0 > 0) ? w0 - 1 : 0;
    const int iR = (w0 < 252) ? w0 + 4 : 255;
#pragma unroll
    for (int j = 0; j < 3; ++j) {
        const int hh = h - 1 + j;
        if (hh < 0 || hh > 255) continue;  // uniform across the wave
        const int rb = hh * 256;
        float xm1 = bf2f(p[rb + iL]) * mL;
        ushort4 mu = *reinterpret_cast<const ushort4*>(p + rb + w0);
        float x0 = bf2f(mu.x), x1 = bf2f(mu.y), x2 = bf2f(mu.z), x3 = bf2f(mu.w);
        float x4 = bf2f(p[rb + iR]) * mR;
        const float wa = wd[j*3+0], wb = wd[j*3+1], wc = wd[j*3+2];
        a0 = fmaf(wa, xm1, a0); a0 = fmaf(wb, x0, a0); a0 = fmaf(wc, x1, a0);
        a1 = fmaf(wa, x0,  a1); a1 = fmaf(wb, x1, a1); a1 = fmaf(wc, x2, a1);
        a2 = fmaf(wa, x1,  a2); a2 = fmaf(wb, x2, a2); a2 = fmaf(wc, x3, a2);
        a3 = fmaf(wa, x2,  a3); a3 = fmaf(wb, x3, a3); a3 = fmaf(wc, x4, a3);
    }
    ushort4 o;
    o.x = f2bf(a0); o.y = f2bf(a1); o.z = f2bf(a2); o.w = f2bf(a3);
    *reinterpret_cast<ushort4*>(vout + (size_t)(b * 64 + ch) * HWN + h * 256 + w0) = o;
}

// ---------------------------------------------------------------------------
// Tiny: norms -> attn softmax -> fold proj: M_t[b][cv][oc] (f32).
// ---------------------------------------------------------------------------
__global__ __launch_bounds__(64) void build_m(const float* __restrict__ ssq_q,
                                              const float* __restrict__ ssq_k,
                                              const float* __restrict__ qk,
                                              const float* __restrict__ temp,
                                              const float* __restrict__ projw,
                                              float* __restrict__ Mt)
{
    const int b = blockIdx.x, t = threadIdx.x;
    __shared__ float attn[8][8][8];  // [head][c][d]
    {
        const int hd = t >> 3, c = t & 7;
        const float nq = fmaxf(sqrtf(ssq_q[b * 64 + hd * 8 + c]), 1e-12f);
        float s[8];
        float mx = -1e30f;
#pragma unroll
        for (int d = 0; d < 8; ++d) {
            const float nk = fmaxf(sqrtf(ssq_k[b * 64 + hd * 8 + d]), 1e-12f);
            s[d] = qk[(size_t)((b*8 + hd)*8 + c) * 8 + d] / (nq * nk) * temp[hd];
            mx = fmaxf(mx, s[d]);
        }
        float sum = 0.f;
#pragma unroll
        for (int d = 0; d < 8; ++d) { s[d] = expf(s[d] - mx); sum += s[d]; }
        const float inv = 1.f / sum;
#pragma unroll
        for (int d = 0; d < 8; ++d) attn[hd][c][d] = s[d] * inv;
    }
    __syncthreads();
    // t = oc; M_t[cv][oc] = sum_cl P[oc][h(cv)*8+cl] * attn[h(cv)][cl][d(cv)]
    for (int hh = 0; hh < 8; ++hh) {
        float p8[8];
#pragma unroll
        for (int cl = 0; cl < 8; ++cl) p8[cl] = projw[t * 64 + hh * 8 + cl];
#pragma unroll
        for (int d = 0; d < 8; ++d) {
            float a = 0.f;
#pragma unroll
            for (int cl = 0; cl < 8; ++cl) a = fmaf(p8[cl], attn[hh][cl][d], a);
            Mt[b * 4096 + (hh * 8 + d) * 64 + t] = a;
        }
    }
}

// ---------------------------------------------------------------------------
extern "C" void kernel_launch(void* const* d_in, const int* in_sizes, int n_in,
                              void* d_out, int out_size, void* d_ws, size_t ws_size,
                              hipStream_t stream)
{
    const float* input1  = (const float*)d_in[0];
    const float* input2  = (const float*)d_in[1];
    const float* q_w     = (const float*)d_in[2];
    const float* q_dw_w  = (const float*)d_in[3];
    const float* kv_w    = (const float*)d_in[4];
    const float* kv_dw_w = (const float*)d_in[5];
    const float* proj_w  = (const float*)d_in[6];
    const float* temp    = (const float*)d_in[7];
    float* out = (float*)d_out;

    char* ws = (char*)d_ws;
    // layout: t_kv (67108864 B) | t_q (33554432 B, reused as v) | accumulators
    u16* t_kv = (u16*)ws;
    u16* t_q  = (u16*)(ws + 67108864);
    u16* v    = t_q;  // alias: t_q dead after qk_dots (stream-ordered)
    float* accs  = (float*)(ws + 100663296);
    float* ssq_q = accs;          // 256
    float* ssq_k = accs + 256;    // 256
    float* qk    = accs + 512;    // 2048
    float* Mt    = accs + 2560;   // 16384
    if (ws_size < 100663296ull + (2560ull + 16384ull) * 4ull) return;

    hipMemsetAsync(accs, 0, 2560 * sizeof(float), stream);

    // K1: t_q = 1x1(input1, q_w)   [bf16 out]
    pw_gemm<64, false, true, true, false><<<dim3(256, 4), 256, 0, stream>>>(input1, q_w, t_q);
    // K2: t_kv = 1x1(input2, kv_w) [bf16 out]
    pw_gemm<128, false, true, true, false><<<dim3(256, 4), 256, 0, stream>>>(input2, kv_w, t_kv);
    // K3: dw(q), dw(k), sumsq, qk dots (atomics)
    qk_dots<<<dim3(32, 8, 4), 256, 0, stream>>>(t_q, t_kv, q_dw_w, kv_dw_w, ssq_q, ssq_k, qk);
    // K4: v = dw(t_v)  (writes into t_q's space)
    dw_v<<<16384, 256, 0, stream>>>(t_kv, kv_dw_w, v);
    // K5: M_t[b] = proj @ blockdiag(softmax(qk/(nq nk) * temp))
    build_m<<<4, 64, 0, stream>>>(ssq_q, ssq_k, qk, temp, proj_w, Mt);
    // K6: out = M_b @ v   [f32 out]
    pw_gemm<64, true, false, false, true><<<dim3(256, 4), 256, 0, stream>>>(v, Mt, out);
}

// Round 3
// 410.374 us; speedup vs baseline: 1.7921x; 1.2051x over previous
//
#include <hip/hip_runtime.h>

// Channel attention block (Restormer MDTA style), B=4 C=64 H=W=256 HEADS=8.
// R2: qk_dots -> two-phase LDS-strip kernel (dw to LDS bf16, Gram from LDS),
// killing the A[64] register wall. pw_gemm weight reads b32 -> b128.

#define HWN 65536
typedef unsigned short u16;

__device__ __forceinline__ float bf2f(u16 u) {
    return __uint_as_float(((unsigned int)u) << 16);
}
__device__ __forceinline__ u16 f2bf(float f) {  // RNE bf16 round
    unsigned int x = __float_as_uint(f);
    x += 0x7FFFu + ((x >> 16) & 1u);
    return (u16)(x >> 16);
}

// ---------------------------------------------------------------------------
// Pointwise (1x1 conv) GEMM: out[b][oc][p] = sum_ic w[ic][oc] * in[b][ic][p]
// block 256 = G ocgroups x T threads; each thread: 16 oc x 4 px register tile.
// ---------------------------------------------------------------------------
template<int OC, bool IN_BF16, bool OUT_BF16, bool W_OIC, bool W_PERB>
__global__ __launch_bounds__(256) void pw_gemm(const void* __restrict__ in_v,
                                               const float* __restrict__ w_g,
                                               void* __restrict__ out_v)
{
    constexpr int G = OC / 16;
    constexpr int T = 256 / G;
    constexpr int PXB = T * 4;
    constexpr int NCHUNK = HWN / PXB;
    __shared__ float wlds[64 * OC];

    const int tid = threadIdx.x;
    const int b = blockIdx.y;
    const float* wsrc = w_g + (W_PERB ? b * 64 * OC : 0);

    for (int idx = tid * 4; idx < 64 * OC; idx += 1024) {
        float4 wv = *reinterpret_cast<const float4*>(wsrc + idx);
        if (W_OIC) {  // global [oc][64] -> lds [ic][OC]
            int oc = idx >> 6, ic0 = idx & 63;
            wlds[(ic0 + 0) * OC + oc] = wv.x;
            wlds[(ic0 + 1) * OC + oc] = wv.y;
            wlds[(ic0 + 2) * OC + oc] = wv.z;
            wlds[(ic0 + 3) * OC + oc] = wv.w;
        } else {      // already [ic][OC]
            *reinterpret_cast<float4*>(&wlds[idx]) = wv;
        }
    }
    __syncthreads();

    const int og = tid / T, tl = tid % T;
    const int ocb = og * 16;
    const size_t inb = (size_t)b * 64 * HWN;

    for (int chunk = blockIdx.x; chunk < NCHUNK; chunk += gridDim.x) {
        const int p0 = chunk * PXB + tl * 4;
        float acc[16][4];
#pragma unroll
        for (int o = 0; o < 16; ++o) {
            acc[o][0] = 0.f; acc[o][1] = 0.f; acc[o][2] = 0.f; acc[o][3] = 0.f;
        }
#pragma unroll 4
        for (int ic = 0; ic < 64; ++ic) {
            float x0, x1, x2, x3;
            if (IN_BF16) {
                ushort4 u = *reinterpret_cast<const ushort4*>(
                    (const u16*)in_v + inb + (size_t)ic * HWN + p0);
                x0 = bf2f(u.x); x1 = bf2f(u.y); x2 = bf2f(u.z); x3 = bf2f(u.w);
            } else {
                float4 f = *reinterpret_cast<const float4*>(
                    (const float*)in_v + inb + (size_t)ic * HWN + p0);
                x0 = f.x; x1 = f.y; x2 = f.z; x3 = f.w;
            }
            // uniform-address LDS broadcast, 4x b128 instead of 16x b32
            const float4 w4a = *reinterpret_cast<const float4*>(&wlds[ic * OC + ocb + 0]);
            const float4 w4b = *reinterpret_cast<const float4*>(&wlds[ic * OC + ocb + 4]);
            const float4 w4c = *reinterpret_cast<const float4*>(&wlds[ic * OC + ocb + 8]);
            const float4 w4d = *reinterpret_cast<const float4*>(&wlds[ic * OC + ocb + 12]);
            const float wv16[16] = {w4a.x, w4a.y, w4a.z, w4a.w,
                                    w4b.x, w4b.y, w4b.z, w4b.w,
                                    w4c.x, w4c.y, w4c.z, w4c.w,
                                    w4d.x, w4d.y, w4d.z, w4d.w};
#pragma unroll
            for (int o = 0; o < 16; ++o) {
                const float wv = wv16[o];
                acc[o][0] = fmaf(wv, x0, acc[o][0]);
                acc[o][1] = fmaf(wv, x1, acc[o][1]);
                acc[o][2] = fmaf(wv, x2, acc[o][2]);
                acc[o][3] = fmaf(wv, x3, acc[o][3]);
            }
        }
#pragma unroll
        for (int o = 0; o < 16; ++o) {
            const size_t ob = ((size_t)b * OC + ocb + o) * HWN + p0;
            if (OUT_BF16) {
                ushort4 u;
                u.x = f2bf(acc[o][0]); u.y = f2bf(acc[o][1]);
                u.z = f2bf(acc[o][2]); u.w = f2bf(acc[o][3]);
                *reinterpret_cast<ushort4*>((u16*)out_v + ob) = u;
            } else {
                float4 f;
                f.x = acc[o][0]; f.y = acc[o][1]; f.z = acc[o][2]; f.w = acc[o][3];
                *reinterpret_cast<float4*>((float*)out_v + ob) = f;
            }
        }
    }
}

// ---------------------------------------------------------------------------
// qk_dots (R2): two-phase strip kernel.
// Phase 1: 4 waves x 4 channels -> dw3x3 of q(8)+k(8) channels over a 4-row
//   strip, results to LDS as bf16. Rows loaded once (+2 halo), shfl w-edges.
// Phase 2: wave w computes Gram slab q{2w,2w+1} x k{0..7} + sumsq from LDS,
//   reduce-scatter butterfly, ~26 atomics/wave. k-sumsq redundant x4 -> *0.25.
// grid (64 strips, 8 heads, 4 b) x 256 threads.
// ---------------------------------------------------------------------------
#define STRIP 4

__global__ __launch_bounds__(256) void qk_dots(const u16* __restrict__ tq,
                                               const u16* __restrict__ tkv,
                                               const float* __restrict__ qdw,
                                               const float* __restrict__ kvdw,
                                               float* __restrict__ ssq_q,
                                               float* __restrict__ ssq_k,
                                               float* __restrict__ qkout)
{
    const int b = blockIdx.z, hd = blockIdx.y;
    const int lane = threadIdx.x & 63, wid = threadIdx.x >> 6;
    const int r0 = blockIdx.x * STRIP;

    __shared__ u16 qklds[16][STRIP * 256];  // ch 0-7 = q, 8-15 = k (bf16)
    __shared__ float wlds[144];             // 0-71 q weights, 72-143 k weights

    if (threadIdx.x < 72)       wlds[threadIdx.x] = qdw[hd * 72 + threadIdx.x];
    else if (threadIdx.x < 144) wlds[threadIdx.x] = kvdw[hd * 72 + (threadIdx.x - 72)];
    __syncthreads();

    const u16* qbase = tq  + (size_t)(b * 64  + hd * 8) * HWN;
    const u16* kbase = tkv + (size_t)(b * 128 + hd * 8) * HWN;
    const int wo = lane * 4;

    // ---- Phase 1: depthwise into LDS ----
#pragma unroll 1
    for (int i = 0; i < 4; ++i) {
        const int gc = wid * 4 + i;                 // 0..15, wave-uniform
        const u16* src = (gc < 8) ? (qbase + (size_t)gc * HWN)
                                  : (kbase + (size_t)(gc - 8) * HWN);
        float wreg[9];
#pragma unroll
        for (int t = 0; t < 9; ++t) wreg[t] = wlds[gc * 9 + t];

        float R[STRIP + 2][6];  // rows r0-1 .. r0+STRIP, [xm1,x0,x1,x2,x3,x4]
#pragma unroll
        for (int jr = 0; jr < STRIP + 2; ++jr) {
            const int hh = r0 - 1 + jr;
            if (hh >= 0 && hh <= 255) {
                ushort4 u = *reinterpret_cast<const ushort4*>(src + hh * 256 + wo);
                float x0 = bf2f(u.x), x1 = bf2f(u.y), x2 = bf2f(u.z), x3 = bf2f(u.w);
                float xm1 = __shfl_up(x3, 1);  if (lane == 0)  xm1 = 0.f;
                float x4  = __shfl_down(x0, 1); if (lane == 63) x4 = 0.f;
                R[jr][0] = xm1; R[jr][1] = x0; R[jr][2] = x1;
                R[jr][3] = x2;  R[jr][4] = x3; R[jr][5] = x4;
            } else {
#pragma unroll
                for (int t = 0; t < 6; ++t) R[jr][t] = 0.f;
            }
        }
#pragma unroll
        for (int o = 0; o < STRIP; ++o) {
            float a0 = 0.f, a1 = 0.f, a2 = 0.f, a3 = 0.f;
#pragma unroll
            for (int t = 0; t < 3; ++t) {
                const float wa = wreg[t * 3 + 0];
                const float wb = wreg[t * 3 + 1];
                const float wc = wreg[t * 3 + 2];
                a0 = fmaf(wa, R[o + t][0], a0); a0 = fmaf(wb, R[o + t][1], a0); a0 = fmaf(wc, R[o + t][2], a0);
                a1 = fmaf(wa, R[o + t][1], a1); a1 = fmaf(wb, R[o + t][2], a1); a1 = fmaf(wc, R[o + t][3], a1);
                a2 = fmaf(wa, R[o + t][2], a2); a2 = fmaf(wb, R[o + t][3], a2); a2 = fmaf(wc, R[o + t][4], a2);
                a3 = fmaf(wa, R[o + t][3], a3); a3 = fmaf(wb, R[o + t][4], a3); a3 = fmaf(wc, R[o + t][5], a3);
            }
            uint2 pk;
            pk.x = (unsigned int)f2bf(a0) | ((unsigned int)f2bf(a1) << 16);
            pk.y = (unsigned int)f2bf(a2) | ((unsigned int)f2bf(a3) << 16);
            *reinterpret_cast<uint2*>(&qklds[gc][o * 256 + wo]) = pk;
        }
    }
    __syncthreads();

    // ---- Phase 2: Gram slab + sumsq from LDS ----
    const int c0 = wid * 2;  // q channels c0, c0+1 for this wave
    float acc[2][8];
#pragma unroll
    for (int d = 0; d < 8; ++d) { acc[0][d] = 0.f; acc[1][d] = 0.f; }
    float sq0 = 0.f, sq1 = 0.f;
    float skk[8] = {0.f, 0.f, 0.f, 0.f, 0.f, 0.f, 0.f, 0.f};

#pragma unroll
    for (int chk = 0; chk < STRIP; ++chk) {
        const int p = chk * 256 + wo;
        uint2 qu0 = *reinterpret_cast<const uint2*>(&qklds[c0 + 0][p]);
        uint2 qu1 = *reinterpret_cast<const uint2*>(&qklds[c0 + 1][p]);
        float q0a = __uint_as_float(qu0.x << 16), q0b = __uint_as_float(qu0.x & 0xffff0000u);
        float q0c = __uint_as_float(qu0.y << 16), q0d = __uint_as_float(qu0.y & 0xffff0000u);
        float q1a = __uint_as_float(qu1.x << 16), q1b = __uint_as_float(qu1.x & 0xffff0000u);
        float q1c = __uint_as_float(qu1.y << 16), q1d = __uint_as_float(qu1.y & 0xffff0000u);
        sq0 = fmaf(q0a, q0a, sq0); sq0 = fmaf(q0b, q0b, sq0);
        sq0 = fmaf(q0c, q0c, sq0); sq0 = fmaf(q0d, q0d, sq0);
        sq1 = fmaf(q1a, q1a, sq1); sq1 = fmaf(q1b, q1b, sq1);
        sq1 = fmaf(q1c, q1c, sq1); sq1 = fmaf(q1d, q1d, sq1);
#pragma unroll
        for (int d = 0; d < 8; ++d) {
            uint2 ku = *reinterpret_cast<const uint2*>(&qklds[8 + d][p]);
            float ka = __uint_as_float(ku.x << 16), kb = __uint_as_float(ku.x & 0xffff0000u);
            float kc = __uint_as_float(ku.y << 16), kd = __uint_as_float(ku.y & 0xffff0000u);
            skk[d] = fmaf(ka, ka, skk[d]); skk[d] = fmaf(kb, kb, skk[d]);
            skk[d] = fmaf(kc, kc, skk[d]); skk[d] = fmaf(kd, kd, skk[d]);
            acc[0][d] = fmaf(q0a, ka, acc[0][d]); acc[0][d] = fmaf(q0b, kb, acc[0][d]);
            acc[0][d] = fmaf(q0c, kc, acc[0][d]); acc[0][d] = fmaf(q0d, kd, acc[0][d]);
            acc[1][d] = fmaf(q1a, ka, acc[1][d]); acc[1][d] = fmaf(q1b, kb, acc[1][d]);
            acc[1][d] = fmaf(q1c, kc, acc[1][d]); acc[1][d] = fmaf(q1d, kd, acc[1][d]);
        }
    }

#define REDSTEP(B, arr)                                                        \
    {                                                                          \
        const bool hi_ = (lane & (B)) != 0;                                    \
        _Pragma("unroll")                                                      \
        for (int i = 0; i < (B); ++i) {                                        \
            float keep_ = hi_ ? arr[i + (B)] : arr[i];                         \
            float send_ = hi_ ? arr[i] : arr[i + (B)];                         \
            arr[i] = keep_ + __shfl_xor(send_, (B));                           \
        }                                                                      \
    }

    // qk dots: 16 values -> lane (l&15) holds total of A16[l&15]
    float A16[16];
#pragma unroll
    for (int d = 0; d < 8; ++d) { A16[d] = acc[0][d]; A16[8 + d] = acc[1][d]; }
    REDSTEP(8, A16) REDSTEP(4, A16) REDSTEP(2, A16) REDSTEP(1, A16)
    {
        float s = A16[0];
        s += __shfl_xor(s, 16);
        s += __shfl_xor(s, 32);
        if (lane < 16) {
            const int cc = c0 + (lane >> 3), dd = lane & 7;
            atomicAdd(qkout + (size_t)(b * 8 + hd) * 64 + cc * 8 + dd, s);
        }
    }
    // sumsq: S[0]=sq(c0) S[1]=sq(c0+1) S[2..9]=skk*0.25
    float S16[16];
    S16[0] = sq0; S16[1] = sq1;
#pragma unroll
    for (int d = 0; d < 8; ++d) S16[2 + d] = skk[d] * 0.25f;
#pragma unroll
    for (int t = 10; t < 16; ++t) S16[t] = 0.f;
    REDSTEP(8, S16) REDSTEP(4, S16) REDSTEP(2, S16) REDSTEP(1, S16)
    {
        float s = S16[0];
        s += __shfl_xor(s, 16);
        s += __shfl_xor(s, 32);
        if (lane < 10) {
            float* dst = (lane < 2) ? (ssq_q + b * 64 + hd * 8 + c0 + lane)
                                    : (ssq_k + b * 64 + hd * 8 + (lane - 2));
            atomicAdd(dst, s);
        }
    }
#undef REDSTEP
}

// ---------------------------------------------------------------------------
// Depthwise 3x3 for v channels (kv channels 64..127), zero pad, bf16 out.
// ---------------------------------------------------------------------------
__global__ __launch_bounds__(256) void dw_v(const u16* __restrict__ tkv,
                                            const float* __restrict__ kvdw,
                                            u16* __restrict__ vout)
{
    const int qid = blockIdx.x * 256 + threadIdx.x;   // 0 .. 4194303
    const int w0 = (qid & 63) * 4;
    const int h  = (qid >> 6) & 255;
    const int ch = (qid >> 14) & 63;
    const int b  = qid >> 20;

    const u16* p = tkv + (size_t)(b * 128 + 64 + ch) * HWN;
    const float* wd = kvdw + (64 + ch) * 9;

    float a0 = 0.f, a1 = 0.f, a2 = 0.f, a3 = 0.f;
    const float mL = (w0 > 0) ? 1.f : 0.f;
    const float mR = (w0 < 252) ? 1.f : 0.f;
    const int iL = (w0 > 0) ? w0 - 1 : 0;
    const int iR = (w0 < 252) ? w0 + 4 : 255;
#pragma unroll
    for (int j = 0; j < 3; ++j) {
        const int hh = h - 1 + j;
        if (hh < 0 || hh > 255) continue;  // uniform across the wave
        const int rb = hh * 256;
        float xm1 = bf2f(p[rb + iL]) * mL;
        ushort4 mu = *reinterpret_cast<const ushort4*>(p + rb + w0);
        float x0 = bf2f(mu.x), x1 = bf2f(mu.y), x2 = bf2f(mu.z), x3 = bf2f(mu.w);
        float x4 = bf2f(p[rb + iR]) * mR;
        const float wa = wd[j*3+0], wb = wd[j*3+1], wc = wd[j*3+2];
        a0 = fmaf(wa, xm1, a0); a0 = fmaf(wb, x0, a0); a0 = fmaf(wc, x1, a0);
        a1 = fmaf(wa, x0,  a1); a1 = fmaf(wb, x1, a1); a1 = fmaf(wc, x2, a1);
        a2 = fmaf(wa, x1,  a2); a2 = fmaf(wb, x2, a2); a2 = fmaf(wc, x3, a2);
        a3 = fmaf(wa, x2,  a3); a3 = fmaf(wb, x3, a3); a3 = fmaf(wc, x4, a3);
    }
    ushort4 o;
    o.x = f2bf(a0); o.y = f2bf(a1); o.z = f2bf(a2); o.w = f2bf(a3);
    *reinterpret_cast<ushort4*>(vout + (size_t)(b * 64 + ch) * HWN + h * 256 + w0) = o;
}

// ---------------------------------------------------------------------------
// Tiny: norms -> attn softmax -> fold proj: M_t[b][cv][oc] (f32).
// ---------------------------------------------------------------------------
__global__ __launch_bounds__(64) void build_m(const float* __restrict__ ssq_q,
                                              const float* __restrict__ ssq_k,
                                              const float* __restrict__ qk,
                                              const float* __restrict__ temp,
                                              const float* __restrict__ projw,
                                              float* __restrict__ Mt)
{
    const int b = blockIdx.x, t = threadIdx.x;
    __shared__ float attn[8][8][8];  // [head][c][d]
    {
        const int hd = t >> 3, c = t & 7;
        const float nq = fmaxf(sqrtf(ssq_q[b * 64 + hd * 8 + c]), 1e-12f);
        float s[8];
        float mx = -1e30f;
#pragma unroll
        for (int d = 0; d < 8; ++d) {
            const float nk = fmaxf(sqrtf(ssq_k[b * 64 + hd * 8 + d]), 1e-12f);
            s[d] = qk[(size_t)((b*8 + hd)*8 + c) * 8 + d] / (nq * nk) * temp[hd];
            mx = fmaxf(mx, s[d]);
        }
        float sum = 0.f;
#pragma unroll
        for (int d = 0; d < 8; ++d) { s[d] = expf(s[d] - mx); sum += s[d]; }
        const float inv = 1.f / sum;
#pragma unroll
        for (int d = 0; d < 8; ++d) attn[hd][c][d] = s[d] * inv;
    }
    __syncthreads();
    // t = oc; M_t[cv][oc] = sum_cl P[oc][h(cv)*8+cl] * attn[h(cv)][cl][d(cv)]
    for (int hh = 0; hh < 8; ++hh) {
        float p8[8];
#pragma unroll
        for (int cl = 0; cl < 8; ++cl) p8[cl] = projw[t * 64 + hh * 8 + cl];
#pragma unroll
        for (int d = 0; d < 8; ++d) {
            float a = 0.f;
#pragma unroll
            for (int cl = 0; cl < 8; ++cl) a = fmaf(p8[cl], attn[hh][cl][d], a);
            Mt[b * 4096 + (hh * 8 + d) * 64 + t] = a;
        }
    }
}

// ---------------------------------------------------------------------------
extern "C" void kernel_launch(void* const* d_in, const int* in_sizes, int n_in,
                              void* d_out, int out_size, void* d_ws, size_t ws_size,
                              hipStream_t stream)
{
    const float* input1  = (const float*)d_in[0];
    const float* input2  = (const float*)d_in[1];
    const float* q_w     = (const float*)d_in[2];
    const float* q_dw_w  = (const float*)d_in[3];
    const float* kv_w    = (const float*)d_in[4];
    const float* kv_dw_w = (const float*)d_in[5];
    const float* proj_w  = (const float*)d_in[6];
    const float* temp    = (const float*)d_in[7];
    float* out = (float*)d_out;

    char* ws = (char*)d_ws;
    // layout: t_kv (67108864 B) | t_q (33554432 B, reused as v) | accumulators
    u16* t_kv = (u16*)ws;
    u16* t_q  = (u16*)(ws + 67108864);
    u16* v    = t_q;  // alias: t_q dead after qk_dots (stream-ordered)
    float* accs  = (float*)(ws + 100663296);
    float* ssq_q = accs;          // 256
    float* ssq_k = accs + 256;    // 256
    float* qk    = accs + 512;    // 2048
    float* Mt    = accs + 2560;   // 16384
    if (ws_size < 100663296ull + (2560ull + 16384ull) * 4ull) return;

    hipMemsetAsync(accs, 0, 2560 * sizeof(float), stream);

    // K1: t_q = 1x1(input1, q_w)   [bf16 out]
    pw_gemm<64, false, true, true, false><<<dim3(256, 4), 256, 0, stream>>>(input1, q_w, t_q);
    // K2: t_kv = 1x1(input2, kv_w) [bf16 out]
    pw_gemm<128, false, true, true, false><<<dim3(256, 4), 256, 0, stream>>>(input2, kv_w, t_kv);
    // K3: dw(q), dw(k), sumsq, qk dots (two-phase LDS strip)
    qk_dots<<<dim3(256 / STRIP, 8, 4), 256, 0, stream>>>(t_q, t_kv, q_dw_w, kv_dw_w, ssq_q, ssq_k, qk);
    // K4: v = dw(t_v)  (writes into t_q's space)
    dw_v<<<16384, 256, 0, stream>>>(t_kv, kv_dw_w, v);
    // K5: M_t[b] = proj @ blockdiag(softmax(qk/(nq nk) * temp))
    build_m<<<4, 64, 0, stream>>>(ssq_q, ssq_k, qk, temp, proj_w, Mt);
    // K6: out = M_b @ v   [f32 out]
    pw_gemm<64, true, false, false, true><<<dim3(256, 4), 256, 0, stream>>>(v, Mt, out);
}